// Round 12
// baseline (2459.569 us; speedup 1.0000x reference)
//
#include <hip/hip_runtime.h>
#include <math.h>

#define VOCAB 20000
#define WORD 620
#define NSEQ 128
#define TMAX 30
#define CTXK 2400
#define XK 3020
#define NBLK 256

typedef unsigned long long u64;
typedef __attribute__((ext_vector_type(8))) short short8;
typedef __attribute__((ext_vector_type(4))) float f32x4;

// ---------- helpers ----------
__device__ __forceinline__ unsigned ford(float f) {
    unsigned b = __float_as_uint(f);
    return (b & 0x80000000u) ? ~b : (b | 0x80000000u);
}
__device__ __forceinline__ unsigned short bf16rne(float x) {
    unsigned u = __float_as_uint(x);
    return (unsigned short)((u + 0x7fffu + ((u >> 16) & 1u)) >> 16);
}
__device__ __forceinline__ float bf16tof(unsigned short h) {
    return __uint_as_float(((unsigned)h) << 16);
}
__device__ __forceinline__ short8 ld8(const unsigned short* p) {
    return *(const short8*)p;
}
#define MFMA(a, b, c) __builtin_amdgcn_mfma_f32_16x16x32_bf16((a), (b), (c), 0, 0, 0)
#define VMW(N) asm volatile("s_waitcnt vmcnt(" #N ")" ::: "memory")

// async 16B/lane global->LDS copy; LDS dest = uniform base + lane*16
__device__ __forceinline__ void gload_lds16(const void* g, void* l) {
    __builtin_amdgcn_global_load_lds((const __attribute__((address_space(1))) void*)g,
                                     (__attribute__((address_space(3))) void*)l,
                                     16, 0, 0);
}

// Two-level grid barrier (round-6 proven): monotonic epochs, RELAXED spin,
// two __threadfence per block per barrier (thread 0 only).
__device__ __forceinline__ void gridbar(unsigned* bar, unsigned epoch) {
    __syncthreads();
    if (threadIdx.x == 0) {
        __threadfence();                // release
        unsigned g = blockIdx.x >> 4;
        unsigned a = __hip_atomic_fetch_add(&bar[g], 1u, __ATOMIC_RELAXED, __HIP_MEMORY_SCOPE_AGENT);
        if (a == epoch * 16u - 1u)
            __hip_atomic_fetch_add(&bar[16], 1u, __ATOMIC_RELAXED, __HIP_MEMORY_SCOPE_AGENT);
        while (__hip_atomic_load(&bar[16], __ATOMIC_RELAXED, __HIP_MEMORY_SCOPE_AGENT) < epoch * 16u)
            __builtin_amdgcn_s_sleep(2);
        __threadfence();                // acquire
    }
    __syncthreads();
}

// =====================================================================
// Shared fragment layout (m91-verified trio), all buffers [tile][ks][2][64][8]:
//   A frag: lane holds A[row = mt*16 + lane%16][k = ks*32 + (lane/16)*8 + j]
//   B frag: lane holds B[col = vt*16 + lane%16][k = ...same...]
//   C/D:    row = (lane>>4)*4 + r, col = lane&15
// =====================================================================

__global__ __launch_bounds__(256) void kpack_w(const float* __restrict__ src,
                                               unsigned short* __restrict__ dst,
                                               int nvt, int nks, int col0,
                                               int ncols_valid, int src_ld,
                                               int nrows_valid, int rowmap) {
    int i = blockIdx.x * 256 + threadIdx.x;
    if (i >= nvt * nks * 512) return;
    int j = i & 7;
    int lane = (i >> 3) & 63;
    int t2 = i >> 9;
    int ks = t2 % nks;
    int vt = t2 / nks;
    int r = vt * 16 + (lane & 15);
    int k = ks * 32 + ((lane >> 4) << 3) + j;
    float x = 0.f;
    if (r < nrows_valid && k < ncols_valid) {
        int row = (rowmap == 1) ? ((r < 620) ? r : r + 620) : r;
        x = src[(size_t)row * src_ld + col0 + k];
    }
    unsigned short hi = bf16rne(x);
    unsigned short lo = bf16rne(x - bf16tof(hi));
    size_t ob = (size_t)t2 * 1024 + lane * 8 + j;
    dst[ob] = hi;
    dst[ob + 512] = lo;
}

__global__ __launch_bounds__(256) void kpack_ctx(const float* __restrict__ th,
                                                 unsigned short* __restrict__ dst) {
    int i = blockIdx.x * 256 + threadIdx.x;
    if (i >= 75 * 8 * 512) return;
    int j = i & 7;
    int lane = (i >> 3) & 63;
    int t2 = i >> 9;
    int mt = t2 & 7;
    int ks = t2 >> 3;
    int n = mt * 16 + (lane & 15);
    int k = ks * 32 + ((lane >> 4) << 3) + j;
    float x = (k < 1200) ? th[(size_t)n * 1200 + k]
                         : th[(size_t)(n + 2) * 1200 + (k - 1200)];
    unsigned short hi = bf16rne(x);
    unsigned short lo = bf16rne(x - bf16tof(hi));
    size_t ob = (size_t)t2 * 1024 + lane * 8 + j;
    dst[ob] = hi;
    dst[ob + 512] = lo;
}

__global__ __launch_bounds__(256) void kpack_embed(const float* __restrict__ embed,
                                                   unsigned short* __restrict__ ehi,
                                                   unsigned short* __restrict__ elo) {
    size_t i = (size_t)blockIdx.x * 256 + threadIdx.x;
    if (i >= (size_t)VOCAB * 640) return;
    int v = (int)(i / 640);
    int k = (int)(i % 640);
    float x = (k < WORD) ? embed[(size_t)v * WORD + k] : 0.f;
    unsigned short hi = bf16rne(x);
    ehi[i] = hi;
    elo[i] = bf16rne(x - bf16tof(hi));
}

// generic frag GEMM (setup only): outT[row][col] = A@B^T (+addRow)
__global__ __launch_bounds__(256) void ggemm(const unsigned short* __restrict__ Af,
                                             const unsigned short* __restrict__ Bf,
                                             const float* __restrict__ addRow,
                                             const float* __restrict__ addFull,
                                             float* __restrict__ outT,
                                             int nks, int nvt, int ldout) {
    int lane = threadIdx.x & 63, wv = threadIdx.x >> 6;
    int vtb = blockIdx.x * 8 + wv * 2;
    bool ok0 = vtb < nvt, ok1 = (vtb + 1) < nvt;
    f32x4 acc[8][2];
#pragma unroll
    for (int m = 0; m < 8; ++m) { acc[m][0] = (f32x4)0.f; acc[m][1] = (f32x4)0.f; }
    if (ok0) {
        const unsigned short* ap = Af + lane * 8;
        const unsigned short* bp0 = Bf + (size_t)vtb * nks * 1024 + lane * 8;
        const unsigned short* bp1 = bp0 + (size_t)nks * 1024;
        for (int ks = 0; ks < nks; ++ks) {
            short8 b0h = ld8(bp0), b0l = ld8(bp0 + 512);
            short8 ah[8], al[8];
#pragma unroll
            for (int m = 0; m < 8; ++m) {
                ah[m] = ld8(ap + m * 1024);
                al[m] = ld8(ap + m * 1024 + 512);
            }
#pragma unroll
            for (int m = 0; m < 8; ++m) {
                acc[m][0] = MFMA(ah[m], b0h, acc[m][0]);
                acc[m][0] = MFMA(ah[m], b0l, acc[m][0]);
                acc[m][0] = MFMA(al[m], b0h, acc[m][0]);
            }
            if (ok1) {
                short8 b1h = ld8(bp1), b1l = ld8(bp1 + 512);
#pragma unroll
                for (int m = 0; m < 8; ++m) {
                    acc[m][1] = MFMA(ah[m], b1h, acc[m][1]);
                    acc[m][1] = MFMA(ah[m], b1l, acc[m][1]);
                    acc[m][1] = MFMA(al[m], b1h, acc[m][1]);
                }
            }
            ap += 8192; bp0 += 1024; bp1 += 1024;
        }
    }
    int rbase = (lane >> 4) << 2;
    int cof = lane & 15;
#pragma unroll
    for (int v = 0; v < 2; ++v) {
        bool ok = v ? ok1 : ok0;
        if (!ok) continue;
        int col = (vtb + v) * 16 + cof;
        float ar = addRow ? addRow[col] : 0.f;
#pragma unroll
        for (int m = 0; m < 8; ++m) {
#pragma unroll
            for (int r = 0; r < 4; ++r) {
                int row = m * 16 + rbase + r;
                float x = acc[m][v][r] + ar;
                if (addFull) x += addFull[(size_t)row * ldout + col];
                outT[(size_t)row * ldout + col] = x;
            }
        }
    }
}

// init for mega path
__global__ __launch_bounds__(256) void kinit3(unsigned* hf32, unsigned* slots32,
                                              float* bsum, unsigned* bar,
                                              const float* __restrict__ b_ih,
                                              const float* __restrict__ b_hh) {
    int i = blockIdx.x * 256 + threadIdx.x;
    if (i < 81920) hf32[i] = 0u;
    if (i < 7680) slots32[i] = 0u;
    if (i < 32) bar[i] = 0u;
    if (i < 1872) {
        float v = 0.f;
        if (i < 1860) {
            int row = (i < 620) ? i : i + 620;   // [i, g, o] -> W_ih rows
            v = b_ih[row] + b_hh[row];
        }
        bsum[i] = v;
    }
}

// =====================================================================
// Persistent decode kernel v9 = round-11 + (a) __launch_bounds__(512,1):
// VGPR cap 256+ so the 160 asm-preloaded B registers actually stay resident
// (round-11's cap of 128 forced them out -> identical perf to round 10);
// (b) G-units placed per-BLOCK (block b<39 owns vt=b, its 8 waves = 8 mt)
// so the 120 KB Wg slice is fetched once per XCD instead of 8x;
// (c) nontemporal out stores. Math bit-identical to rounds 6/10/11.
// =====================================================================
__global__ __launch_bounds__(512, 1) void kmega(
    const unsigned short* __restrict__ embhi,
    const unsigned short* __restrict__ emblo,
    const unsigned short* __restrict__ Wgf3,
    const unsigned short* __restrict__ Wwf,
    const float* __restrict__ base,
    const float* __restrict__ bw,
    unsigned short* __restrict__ hf,
    u64* __restrict__ slots,
    float* __restrict__ out,
    unsigned* bar) {
    __shared__ char sA[5][16384];
    __shared__ u64 keybuf[128];
    const int tid = threadIdx.x;
    const int lane = tid & 63;
    const int wv = tid >> 6;                   // 0..7
    const int bid = blockIdx.x;

    const int vt_lo = (int)(((long long)bid * 1250) / NBLK);
    const int vt_hi = (int)(((long long)(bid + 1) * 1250) / NBLK);
    const int nvt = vt_hi - vt_lo;             // 4 or 5
    const bool act = (wv < nvt);               // wave owns one vt
    const int myvt = vt_lo + (act ? wv : 0);
    const bool gact = (bid < 39);              // block owns G-vt = bid, wave = mt

    // ---- preload this wave's B fragments into registers (inline asm:
    // cannot be sunk or rematerialized; with cap>=256 they stay resident) ----
    short8 Bh[20], Bl[20];
    {
        const unsigned short* bp = Wwf + (size_t)myvt * 20480 + lane * 8;
#pragma unroll
        for (int ks = 0; ks < 20; ++ks) {
            asm volatile("global_load_dwordx4 %0, %2, off\n\t"
                         "global_load_dwordx4 %1, %2, off offset:1024"
                         : "=&v"(Bh[ks]), "=&v"(Bl[ks])
                         : "v"(bp + (size_t)ks * 1024));
        }
        VMW(0);   // drain preload; in-loop vmcnt literals count only stage loads
    }

    const char* hfb = (const char*)hf;
    unsigned epoch = 0;

#define LSTEP(KS, WN)                                                          \
    do {                                                                       \
        if ((KS) + 3 < 20) {                                                   \
            const char* gsrc = hfb + (size_t)((KS) + 3) * 16384 +              \
                               (wv * 2) * 1024 + lane * 16;                    \
            char* ldst = sA[((KS) + 3) % 5] + (wv * 2) * 1024;                 \
            gload_lds16(gsrc, ldst);                                           \
            gload_lds16(gsrc + 1024, ldst + 1024);                             \
        }                                                                      \
        __builtin_amdgcn_sched_barrier(0);                                     \
        VMW(WN);                                                               \
        __builtin_amdgcn_s_barrier();                                          \
        __builtin_amdgcn_sched_barrier(0);                                     \
        {                                                                      \
            const unsigned short* ab = (const unsigned short*)sA[(KS) % 5];    \
            if (act) {                                                         \
                _Pragma("unroll")                                              \
                for (int mt = 0; mt < 8; ++mt) {                               \
                    short8 ah = ld8(ab + mt * 1024 + lane * 8);                \
                    short8 al = ld8(ab + mt * 1024 + 512 + lane * 8);          \
                    acc[mt] = MFMA(ah, Bh[KS], acc[mt]);                       \
                    acc[mt] = MFMA(ah, Bl[KS], acc[mt]);                       \
                    acc[mt] = MFMA(al, Bh[KS], acc[mt]);                       \
                }                                                              \
            }                                                                  \
        }                                                                      \
    } while (0)

    for (int t = 0; t < TMAX; ++t) {
        // ---------- G: gates + activation -> hf (block-local vt) ----------
        if (gact) {
            const int g_vt = bid;              // 0..38
            const int g_mt = wv;               // 0..7
            f32x4 aI = (f32x4)0.f, aG = (f32x4)0.f, aO = (f32x4)0.f;
            if (t > 0) {
                int n = g_mt * 16 + (lane & 15);
                u64 s = slots[(size_t)(t - 1) * NSEQ + n];
                unsigned idx = 0xFFFFFFFFu - (unsigned)(s & 0xFFFFFFFFull);
                const unsigned short* eh = embhi + (size_t)idx * 640 + ((lane >> 4) << 3);
                const unsigned short* el = emblo + (size_t)idx * 640 + ((lane >> 4) << 3);
                const unsigned short* bI = Wgf3 + (size_t)(0 * 39 + g_vt) * 20480 + lane * 8;
                const unsigned short* bG = Wgf3 + (size_t)(1 * 39 + g_vt) * 20480 + lane * 8;
                const unsigned short* bO = Wgf3 + (size_t)(2 * 39 + g_vt) * 20480 + lane * 8;
#pragma unroll 2
                for (int ks = 0; ks < 20; ++ks) {
                    short8 ah = ld8(eh + ks * 32);
                    short8 al = ld8(el + ks * 32);
                    short8 bIh = ld8(bI), bIl = ld8(bI + 512);
                    short8 bGh = ld8(bG), bGl = ld8(bG + 512);
                    short8 bOh = ld8(bO), bOl = ld8(bO + 512);
                    aI = MFMA(ah, bIh, aI); aI = MFMA(ah, bIl, aI); aI = MFMA(al, bIh, aI);
                    aG = MFMA(ah, bGh, aG); aG = MFMA(ah, bGl, aG); aG = MFMA(al, bGh, aG);
                    aO = MFMA(ah, bOh, aO); aO = MFMA(ah, bOl, aO); aO = MFMA(al, bOh, aO);
                    bI += 1024; bG += 1024; bO += 1024;
                }
            }
            int col = g_vt * 16 + (lane & 15);
            if (col < WORD) {
                int rbase = g_mt * 16 + ((lane >> 4) << 2);
#pragma unroll
                for (int r = 0; r < 4; ++r) {
                    int n = rbase + r;
                    float gi = aI[r] + base[(size_t)n * 1872 + col];
                    float gg = aG[r] + base[(size_t)n * 1872 + 620 + col];
                    float go = aO[r] + base[(size_t)n * 1872 + 1240 + col];
                    float si = 1.f / (1.f + expf(-gi));
                    float so = 1.f / (1.f + expf(-go));
                    float h = so * tanhf(si * tanhf(gg));
                    int pos = (((col >> 5) * 8 + (n >> 4)) * 1024) +
                              (((n & 15) + (((col & 31) >> 3) << 4)) * 8) + (col & 7);
                    unsigned short hi = bf16rne(h);
                    hf[pos] = hi;
                    hf[pos + 512] = bf16rne(h - bf16tof(hi));
                }
            }
        }
        if (tid < 128) keybuf[tid] = 0ull;
        ++epoch;
        gridbar(bar, epoch);                // hf ready everywhere; vmcnt=0

        // ---------- L: B-in-registers, A staged depth-3 via 5 LDS bufs ----------
        f32x4 acc[8];
#pragma unroll
        for (int mt = 0; mt < 8; ++mt) acc[mt] = (f32x4)0.f;

        // prologue: stage A-chunks 0,1,2 (2 lines per wave each)
        {
            const char* g0 = hfb + (wv * 2) * 1024 + lane * 16;
            char* l0 = sA[0] + (wv * 2) * 1024;
            gload_lds16(g0, l0);
            gload_lds16(g0 + 1024, l0 + 1024);
            const char* g1 = hfb + 16384 + (wv * 2) * 1024 + lane * 16;
            char* l1 = sA[1] + (wv * 2) * 1024;
            gload_lds16(g1, l1);
            gload_lds16(g1 + 1024, l1 + 1024);
            const char* g2 = hfb + 2 * 16384 + (wv * 2) * 1024 + lane * 16;
            char* l2 = sA[2] + (wv * 2) * 1024;
            gload_lds16(g2, l2);
            gload_lds16(g2 + 1024, l2 + 1024);
        }
        __builtin_amdgcn_sched_barrier(0);

        LSTEP(0, 6);  LSTEP(1, 6);  LSTEP(2, 6);  LSTEP(3, 6);  LSTEP(4, 6);
        LSTEP(5, 6);  LSTEP(6, 6);  LSTEP(7, 6);  LSTEP(8, 6);  LSTEP(9, 6);
        LSTEP(10, 6); LSTEP(11, 6); LSTEP(12, 6); LSTEP(13, 6); LSTEP(14, 6);
        LSTEP(15, 6); LSTEP(16, 6); LSTEP(17, 4); LSTEP(18, 2); LSTEP(19, 0);

        int q = lane >> 4, cof = lane & 15;
        if (act) {
            int v = myvt * 16 + cof;
            float bwv = bw[v];
#pragma unroll
            for (int mt = 0; mt < 8; ++mt) {
#pragma unroll
                for (int r = 0; r < 4; ++r) {
                    int n = mt * 16 + q * 4 + r;
                    float x = acc[mt][r] + bwv;
                    __builtin_nontemporal_store(x, &out[((size_t)n * TMAX + t) * VOCAB + v]);
                    u64 key = ((u64)ford(x) << 32) | (u64)(0xFFFFFFFFu - (unsigned)v);
#pragma unroll
                    for (int s2 = 1; s2 <= 8; s2 <<= 1) {
                        u64 o = __shfl_xor(key, s2, 64);
                        if (o > key) key = o;
                    }
                    if (cof == 0) atomicMax(&keybuf[n], key);
                }
            }
        }
        __syncthreads();
        if (tid < 128) {
            u64 k = keybuf[tid];
            if (k) atomicMax(&slots[(size_t)t * NSEQ + tid], k);
        }
        if (t + 1 < TMAX) {
            ++epoch;
            gridbar(bar, epoch);            // slots[t] ready everywhere
        }
    }
#undef LSTEP
}

// =====================================================================
// fallback (round-2 proven path) — used only if ws too small for mega
// =====================================================================
__global__ __launch_bounds__(256) void kinit2(unsigned int* lastfrag32,
                                              unsigned int* hfrag32,
                                              unsigned int* slots32,
                                              float* bsum,
                                              const float* __restrict__ b_ih,
                                              const float* __restrict__ b_hh) {
    int i = blockIdx.x * 256 + threadIdx.x;
    if (i < 81920) { lastfrag32[i] = 0u; hfrag32[i] = 0u; }
    if (i < 7680) slots32[i] = 0u;
    if (i < 1872) {
        float v = 0.f;
        if (i < 1860) {
            int row = (i < 620) ? i : i + 620;
            v = b_ih[row] + b_hh[row];
        }
        bsum[i] = v;
    }
}

__global__ __launch_bounds__(256) void klogits2(const unsigned short* __restrict__ Hf,
                                                const unsigned short* __restrict__ Wf,
                                                const float* __restrict__ bw,
                                                float* __restrict__ out,
                                                u64* __restrict__ slots, int t) {
    __shared__ u64 keybuf[128];
    int tid = threadIdx.x;
    if (tid < 128) keybuf[tid] = 0ull;
    __syncthreads();
    int lane = tid & 63, wv = tid >> 6;
    int vtb = blockIdx.x * 8 + wv * 2;
    bool ok0 = vtb < 1250, ok1 = (vtb + 1) < 1250;
    f32x4 acc[8][2];
#pragma unroll
    for (int m = 0; m < 8; ++m) { acc[m][0] = (f32x4)0.f; acc[m][1] = (f32x4)0.f; }
    if (ok0) {
        const unsigned short* ap = Hf + lane * 8;
        const unsigned short* bp0 = Wf + (size_t)vtb * 20 * 1024 + lane * 8;
        const unsigned short* bp1 = bp0 + 20 * 1024;
#pragma unroll 2
        for (int ks = 0; ks < 20; ++ks) {
            short8 b0h = ld8(bp0), b0l = ld8(bp0 + 512);
            short8 ah[8], al[8];
#pragma unroll
            for (int m = 0; m < 8; ++m) {
                ah[m] = ld8(ap + m * 1024);
                al[m] = ld8(ap + m * 1024 + 512);
            }
#pragma unroll
            for (int m = 0; m < 8; ++m) {
                acc[m][0] = MFMA(ah[m], b0h, acc[m][0]);
                acc[m][0] = MFMA(ah[m], b0l, acc[m][0]);
                acc[m][0] = MFMA(al[m], b0h, acc[m][0]);
            }
            if (ok1) {
                short8 b1h = ld8(bp1), b1l = ld8(bp1 + 512);
#pragma unroll
                for (int m = 0; m < 8; ++m) {
                    acc[m][1] = MFMA(ah[m], b1h, acc[m][1]);
                    acc[m][1] = MFMA(ah[m], b1l, acc[m][1]);
                    acc[m][1] = MFMA(al[m], b1h, acc[m][1]);
                }
            }
            ap += 8192; bp0 += 1024; bp1 += 1024;
        }
    }
    int rbase = (lane >> 4) << 2;
    int cof = lane & 15;
    float bw0 = ok0 ? bw[vtb * 16 + cof] : 0.f;
    float bw1 = ok1 ? bw[(vtb + 1) * 16 + cof] : 0.f;
#pragma unroll
    for (int m = 0; m < 8; ++m) {
#pragma unroll
        for (int r = 0; r < 4; ++r) {
            int row = m * 16 + rbase + r;
            u64 km = 0ull;
            if (ok0) {
                int v = vtb * 16 + cof;
                float x = acc[m][0][r] + bw0;
                out[((size_t)row * TMAX + t) * VOCAB + v] = x;
                km = ((u64)ford(x) << 32) | (u64)(0xFFFFFFFFu - (unsigned)v);
            }
            if (ok1) {
                int v = (vtb + 1) * 16 + cof;
                float x = acc[m][1][r] + bw1;
                out[((size_t)row * TMAX + t) * VOCAB + v] = x;
                u64 k2 = ((u64)ford(x) << 32) | (u64)(0xFFFFFFFFu - (unsigned)v);
                if (k2 > km) km = k2;
            }
#pragma unroll
            for (int s2 = 1; s2 <= 8; s2 <<= 1) {
                u64 o = __shfl_xor(km, s2, 64);
                if (o > km) km = o;
            }
            if ((lane & 15) == 0 && km) atomicMax(&keybuf[row], km);
        }
    }
    __syncthreads();
    if (tid < 128) atomicMax(&slots[(size_t)t * NSEQ + tid], keybuf[tid]);
}

__global__ void kact(const float* __restrict__ gates,
                     unsigned short* __restrict__ hfrag) {
    int n = blockIdx.x;
    int k = threadIdx.x;
    if (k >= WORD) return;
    const float* g = gates + (size_t)n * 1872;
    float gi = g[k], gg = g[620 + k], go = g[1240 + k];
    float si = 1.f / (1.f + expf(-gi));
    float so = 1.f / (1.f + expf(-go));
    float h = so * tanhf(si * tanhf(gg));
    int ks = k >> 5, mt = n >> 4;
    int lane = (n & 15) + (((k & 31) >> 3) << 4);
    int j = k & 7;
    size_t ob = (size_t)(ks * 8 + mt) * 1024 + lane * 8 + j;
    unsigned short hi = bf16rne(h);
    hfrag[ob] = hi;
    hfrag[ob + 512] = bf16rne(h - bf16tof(hi));
}

__global__ void kgather2(const float* __restrict__ embed,
                         const u64* __restrict__ slots,
                         unsigned short* __restrict__ lastfrag, int t) {
    int n = blockIdx.x;
    int k = threadIdx.x;
    if (k >= WORD) return;
    u64 s = slots[(size_t)t * NSEQ + n];
    unsigned idx = 0xFFFFFFFFu - (unsigned)(s & 0xFFFFFFFFull);
    float x = embed[(size_t)idx * WORD + k];
    int ks = k >> 5, mt = n >> 4;
    int lane = (n & 15) + (((k & 31) >> 3) << 4);
    int j = k & 7;
    size_t ob = (size_t)(ks * 8 + mt) * 1024 + lane * 8 + j;
    unsigned short hi = bf16rne(x);
    lastfrag[ob] = hi;
    lastfrag[ob + 512] = bf16rne(x - bf16tof(hi));
}

// =====================================================================
extern "C" void kernel_launch(void* const* d_in, const int* in_sizes, int n_in,
                              void* d_out, int out_size, void* d_ws, size_t ws_size,
                              hipStream_t stream) {
    const float* thoughts = (const float*)d_in[0];
    const float* embed    = (const float*)d_in[1];
    const float* W_ih     = (const float*)d_in[2];
    // d_in[3] = W_hh: dead (h0 == 0 always)
    const float* b_ih     = (const float*)d_in[4];
    const float* b_hh     = (const float*)d_in[5];
    const float* Ww       = (const float*)d_in[6];
    const float* bw       = (const float*)d_in[7];
    float* out = (float*)d_out;
    char* ws = (char*)d_ws;

    // mega layout (round-6)
    const size_t OFF_WWF  = 0;              // 51,200,000
    const size_t OFF_WBF  = 51200000;       // 17,971,200
    const size_t OFF_WGF3 = 69171200;       //  4,792,320
    const size_t OFF_CTXF = 73963520;       //  1,228,800
    const size_t OFF_EHI  = 75192320;       // 25,600,000
    const size_t OFF_ELO  = 100792320;      // 25,600,000
    const size_t OFF_HF   = 126392320;      //    327,680
    const size_t OFF_BASE = 126720000;      //    958,464
    const size_t OFF_BSUM = 127678464;      //      7,488
    const size_t OFF_SLOT = 127685952;      //     30,720
    const size_t OFF_BAR  = 127716672;      //        128
    const size_t NEED_MEGA = 127716800;

    if (ws_size >= NEED_MEGA) {
        unsigned short* Wwf  = (unsigned short*)(ws + OFF_WWF);
        unsigned short* Wbf  = (unsigned short*)(ws + OFF_WBF);
        unsigned short* Wgf3 = (unsigned short*)(ws + OFF_WGF3);
        unsigned short* ctxf = (unsigned short*)(ws + OFF_CTXF);
        unsigned short* ehi  = (unsigned short*)(ws + OFF_EHI);
        unsigned short* elo  = (unsigned short*)(ws + OFF_ELO);
        unsigned short* hf   = (unsigned short*)(ws + OFF_HF);
        float* base = (float*)(ws + OFF_BASE);
        float* bsum = (float*)(ws + OFF_BSUM);
        u64*   slots = (u64*)(ws + OFF_SLOT);
        unsigned* bar = (unsigned*)(ws + OFF_BAR);

        kinit3<<<320, 256, 0, stream>>>((unsigned*)hf, (unsigned*)slots, bsum, bar, b_ih, b_hh);
        kpack_w<<<50000, 256, 0, stream>>>(Ww, Wwf, 1250, 20, 0, 620, WORD, VOCAB, 0);
        kpack_w<<<17550, 256, 0, stream>>>(W_ih, Wbf, 117, 75, 0, 2400, XK, 1860, 1);
        kpack_w<<<1560, 256, 0, stream>>>(W_ih + (size_t)0 * XK,    Wgf3 + 0 * 798720, 39, 20, 2400, 620, XK, 620, 0);
        kpack_w<<<1560, 256, 0, stream>>>(W_ih + (size_t)1240 * XK, Wgf3 + 1 * 798720, 39, 20, 2400, 620, XK, 620, 0);
        kpack_w<<<1560, 256, 0, stream>>>(W_ih + (size_t)1860 * XK, Wgf3 + 2 * 798720, 39, 20, 2400, 620, XK, 620, 0);
        kpack_ctx<<<1200, 256, 0, stream>>>(thoughts, ctxf);
        kpack_embed<<<50000, 256, 0, stream>>>(embed, ehi, elo);
        ggemm<<<15, 256, 0, stream>>>(ctxf, Wbf, bsum, nullptr, base, 75, 117, 1872);

        kmega<<<NBLK, 512, 0, stream>>>(ehi, elo, Wgf3, Wwf, base, bw, hf, slots, out, bar);
    } else {
        // round-2 fallback layout
        const size_t F_WWF  = 0;
        const size_t F_WBF  = 51200000;
        const size_t F_WGF  = 69171200;
        const size_t F_CTXF = 73963520;
        const size_t F_HF   = 75192320;
        const size_t F_LF   = 75520000;
        const size_t F_BASE = 75847680;
        const size_t F_GATE = 76806144;
        const size_t F_BSUM = 77764608;
        const size_t F_SLOT = 77772096;

        unsigned short* Wwf  = (unsigned short*)(ws + F_WWF);
        unsigned short* Wbf  = (unsigned short*)(ws + F_WBF);
        unsigned short* Wgf  = (unsigned short*)(ws + F_WGF);
        unsigned short* ctxf = (unsigned short*)(ws + F_CTXF);
        unsigned short* hf   = (unsigned short*)(ws + F_HF);
        unsigned short* lf   = (unsigned short*)(ws + F_LF);
        float* base = (float*)(ws + F_BASE);
        float* gate = (float*)(ws + F_GATE);
        float* bsum = (float*)(ws + F_BSUM);
        u64*   slots = (u64*)(ws + F_SLOT);

        kinit2<<<320, 256, 0, stream>>>((unsigned int*)lf, (unsigned int*)hf,
                                        (unsigned int*)slots, bsum, b_ih, b_hh);
        kpack_w<<<50000, 256, 0, stream>>>(Ww, Wwf, 1250, 20, 0, 620, WORD, VOCAB, 0);
        kpack_w<<<17550, 256, 0, stream>>>(W_ih, Wbf, 117, 75, 0, 2400, XK, 1860, 1);
        kpack_w<<<4680, 256, 0, stream>>>(W_ih, Wgf, 117, 20, 2400, 620, XK, 1860, 1);
        kpack_ctx<<<1200, 256, 0, stream>>>(thoughts, ctxf);
        ggemm<<<15, 256, 0, stream>>>(ctxf, Wbf, bsum, nullptr, base, 75, 117, 1872);
        for (int t = 0; t < TMAX; ++t) {
            ggemm<<<15, 256, 0, stream>>>(lf, Wgf, nullptr, base, gate, 20, 117, 1872);
            kact<<<NSEQ, 640, 0, stream>>>(gate, hf);
            klogits2<<<157, 256, 0, stream>>>(hf, Wwf, bw, out, slots, t);
            if (t + 1 < TMAX)
                kgather2<<<NSEQ, 640, 0, stream>>>(embed, slots, lf, t);
        }
    }
}

// Round 13
// 1770.734 us; speedup vs baseline: 1.3890x; 1.3890x over previous
//
#include <hip/hip_runtime.h>
#include <math.h>

#define VOCAB 20000
#define WORD 620
#define NSEQ 128
#define TMAX 30
#define CTXK 2400
#define XK 3020
#define NBLK 256

typedef unsigned long long u64;
typedef __attribute__((ext_vector_type(8))) short short8;
typedef __attribute__((ext_vector_type(4))) float f32x4;

// ---------- helpers ----------
__device__ __forceinline__ unsigned ford(float f) {
    unsigned b = __float_as_uint(f);
    return (b & 0x80000000u) ? ~b : (b | 0x80000000u);
}
__device__ __forceinline__ unsigned short bf16rne(float x) {
    unsigned u = __float_as_uint(x);
    return (unsigned short)((u + 0x7fffu + ((u >> 16) & 1u)) >> 16);
}
__device__ __forceinline__ float bf16tof(unsigned short h) {
    return __uint_as_float(((unsigned)h) << 16);
}
__device__ __forceinline__ short8 ld8(const unsigned short* p) {
    return *(const short8*)p;
}
#define MFMA(a, b, c) __builtin_amdgcn_mfma_f32_16x16x32_bf16((a), (b), (c), 0, 0, 0)
#define VMW(N) asm volatile("s_waitcnt vmcnt(" #N ")" ::: "memory")
#define AL64(p) __hip_atomic_load((p), __ATOMIC_RELAXED, __HIP_MEMORY_SCOPE_AGENT)

// Grid barrier v4: 16 group counters on SEPARATE cache lines (bar[g*16]) +
// root (bar[256]) -> arrivals parallelize across 16 lines instead of
// serializing 256 RMWs on one line. NO acquire fence ever (cross-step data
// is read via agent-scope atomic loads that bypass the non-coherent L2);
// release fence only when `rel` (G-blocks flushing their hf stores to IC).
__device__ __forceinline__ void gridbar(unsigned* bar, unsigned epoch, bool rel) {
    __syncthreads();                    // drains vmcnt: stores/atomics acked
    if (threadIdx.x == 0) {
        if (rel) __threadfence();       // wbl2: push dirty hf lines to IC
        unsigned g = blockIdx.x >> 4;
        unsigned a = __hip_atomic_fetch_add(&bar[g * 16], 1u, __ATOMIC_RELAXED, __HIP_MEMORY_SCOPE_AGENT);
        if (a == epoch * 16u - 1u)
            __hip_atomic_fetch_add(&bar[256], 1u, __ATOMIC_RELAXED, __HIP_MEMORY_SCOPE_AGENT);
        while (__hip_atomic_load(&bar[256], __ATOMIC_RELAXED, __HIP_MEMORY_SCOPE_AGENT) < epoch * 16u)
            __builtin_amdgcn_s_sleep(2);
    }
    __syncthreads();
}

// =====================================================================
// Shared fragment layout (m91-verified trio), all buffers [tile][ks][2][64][8]:
//   A frag: lane holds A[row = mt*16 + lane%16][k = ks*32 + (lane/16)*8 + j]
//   B frag: lane holds B[col = vt*16 + lane%16][k = ...same...]
//   C/D:    row = (lane>>4)*4 + r, col = lane&15
// =====================================================================

__global__ __launch_bounds__(256) void kpack_w(const float* __restrict__ src,
                                               unsigned short* __restrict__ dst,
                                               int nvt, int nks, int col0,
                                               int ncols_valid, int src_ld,
                                               int nrows_valid, int rowmap) {
    int i = blockIdx.x * 256 + threadIdx.x;
    if (i >= nvt * nks * 512) return;
    int j = i & 7;
    int lane = (i >> 3) & 63;
    int t2 = i >> 9;
    int ks = t2 % nks;
    int vt = t2 / nks;
    int r = vt * 16 + (lane & 15);
    int k = ks * 32 + ((lane >> 4) << 3) + j;
    float x = 0.f;
    if (r < nrows_valid && k < ncols_valid) {
        int row = (rowmap == 1) ? ((r < 620) ? r : r + 620) : r;
        x = src[(size_t)row * src_ld + col0 + k];
    }
    unsigned short hi = bf16rne(x);
    unsigned short lo = bf16rne(x - bf16tof(hi));
    size_t ob = (size_t)t2 * 1024 + lane * 8 + j;
    dst[ob] = hi;
    dst[ob + 512] = lo;
}

__global__ __launch_bounds__(256) void kpack_ctx(const float* __restrict__ th,
                                                 unsigned short* __restrict__ dst) {
    int i = blockIdx.x * 256 + threadIdx.x;
    if (i >= 75 * 8 * 512) return;
    int j = i & 7;
    int lane = (i >> 3) & 63;
    int t2 = i >> 9;
    int mt = t2 & 7;
    int ks = t2 >> 3;
    int n = mt * 16 + (lane & 15);
    int k = ks * 32 + ((lane >> 4) << 3) + j;
    float x = (k < 1200) ? th[(size_t)n * 1200 + k]
                         : th[(size_t)(n + 2) * 1200 + (k - 1200)];
    unsigned short hi = bf16rne(x);
    unsigned short lo = bf16rne(x - bf16tof(hi));
    size_t ob = (size_t)t2 * 1024 + lane * 8 + j;
    dst[ob] = hi;
    dst[ob + 512] = lo;
}

__global__ __launch_bounds__(256) void kpack_embed(const float* __restrict__ embed,
                                                   unsigned short* __restrict__ ehi,
                                                   unsigned short* __restrict__ elo) {
    size_t i = (size_t)blockIdx.x * 256 + threadIdx.x;
    if (i >= (size_t)VOCAB * 640) return;
    int v = (int)(i / 640);
    int k = (int)(i % 640);
    float x = (k < WORD) ? embed[(size_t)v * WORD + k] : 0.f;
    unsigned short hi = bf16rne(x);
    ehi[i] = hi;
    elo[i] = bf16rne(x - bf16tof(hi));
}

// generic frag GEMM (setup only): outT[row][col] = A@B^T (+addRow)
__global__ __launch_bounds__(256) void ggemm(const unsigned short* __restrict__ Af,
                                             const unsigned short* __restrict__ Bf,
                                             const float* __restrict__ addRow,
                                             const float* __restrict__ addFull,
                                             float* __restrict__ outT,
                                             int nks, int nvt, int ldout) {
    int lane = threadIdx.x & 63, wv = threadIdx.x >> 6;
    int vtb = blockIdx.x * 8 + wv * 2;
    bool ok0 = vtb < nvt, ok1 = (vtb + 1) < nvt;
    f32x4 acc[8][2];
#pragma unroll
    for (int m = 0; m < 8; ++m) { acc[m][0] = (f32x4)0.f; acc[m][1] = (f32x4)0.f; }
    if (ok0) {
        const unsigned short* ap = Af + lane * 8;
        const unsigned short* bp0 = Bf + (size_t)vtb * nks * 1024 + lane * 8;
        const unsigned short* bp1 = bp0 + (size_t)nks * 1024;
        for (int ks = 0; ks < nks; ++ks) {
            short8 b0h = ld8(bp0), b0l = ld8(bp0 + 512);
            short8 ah[8], al[8];
#pragma unroll
            for (int m = 0; m < 8; ++m) {
                ah[m] = ld8(ap + m * 1024);
                al[m] = ld8(ap + m * 1024 + 512);
            }
#pragma unroll
            for (int m = 0; m < 8; ++m) {
                acc[m][0] = MFMA(ah[m], b0h, acc[m][0]);
                acc[m][0] = MFMA(ah[m], b0l, acc[m][0]);
                acc[m][0] = MFMA(al[m], b0h, acc[m][0]);
            }
            if (ok1) {
                short8 b1h = ld8(bp1), b1l = ld8(bp1 + 512);
#pragma unroll
                for (int m = 0; m < 8; ++m) {
                    acc[m][1] = MFMA(ah[m], b1h, acc[m][1]);
                    acc[m][1] = MFMA(ah[m], b1l, acc[m][1]);
                    acc[m][1] = MFMA(al[m], b1h, acc[m][1]);
                }
            }
            ap += 8192; bp0 += 1024; bp1 += 1024;
        }
    }
    int rbase = (lane >> 4) << 2;
    int cof = lane & 15;
#pragma unroll
    for (int v = 0; v < 2; ++v) {
        bool ok = v ? ok1 : ok0;
        if (!ok) continue;
        int col = (vtb + v) * 16 + cof;
        float ar = addRow ? addRow[col] : 0.f;
#pragma unroll
        for (int m = 0; m < 8; ++m) {
#pragma unroll
            for (int r = 0; r < 4; ++r) {
                int row = m * 16 + rbase + r;
                float x = acc[m][v][r] + ar;
                if (addFull) x += addFull[(size_t)row * ldout + col];
                outT[(size_t)row * ldout + col] = x;
            }
        }
    }
}

// init for mega path (bar now 512 u32)
__global__ __launch_bounds__(256) void kinit3(unsigned* hf32, unsigned* slots32,
                                              float* bsum, unsigned* bar,
                                              const float* __restrict__ b_ih,
                                              const float* __restrict__ b_hh) {
    int i = blockIdx.x * 256 + threadIdx.x;
    if (i < 81920) hf32[i] = 0u;
    if (i < 7680) slots32[i] = 0u;
    if (i < 512) bar[i] = 0u;
    if (i < 1872) {
        float v = 0.f;
        if (i < 1860) {
            int row = (i < 620) ? i : i + 620;   // [i, g, o] -> W_ih rows
            v = b_ih[row] + b_hh[row];
        }
        bsum[i] = v;
    }
}

// =====================================================================
// Persistent decode kernel v10: no-fence barrier (spread counters), hf/slots
// read via agent-scope atomic loads (L2-bypass), release fence only on the
// 39 G-blocks -> Ww/Wg/base stay L2-resident across steps. A(hf) reg-staged
// depth-2 into 3 LDS buffers; B double-buffered per-wave in 3 register slots.
// Math bit-identical to round 6 (same 3-MFMA split-bf16, ks ascending).
// =====================================================================
__global__ __launch_bounds__(512, 2) void kmega(
    const unsigned short* __restrict__ embhi,
    const unsigned short* __restrict__ emblo,
    const unsigned short* __restrict__ Wgf3,
    const unsigned short* __restrict__ Wwf,
    const float* __restrict__ base,
    const float* __restrict__ bw,
    unsigned short* __restrict__ hf,
    u64* __restrict__ slots,
    float* __restrict__ out,
    unsigned* bar) {
    __shared__ char sA[3][16384];
    __shared__ u64 keybuf[128];
    const int tid = threadIdx.x;
    const int lane = tid & 63;
    const int wv = tid >> 6;                   // 0..7
    const int bid = blockIdx.x;

    const int vt_lo = (int)(((long long)bid * 1250) / NBLK);
    const int vt_hi = (int)(((long long)(bid + 1) * 1250) / NBLK);
    const int nvt = vt_hi - vt_lo;             // 4 or 5
    const bool act = (wv < nvt);               // wave owns one vt
    const int myvt = vt_lo + (act ? wv : 0);
    const bool gact = (bid < 39);              // block owns G-vt = bid, wave = mt

    const char* hfb = (const char*)hf;
    const unsigned short* Bbase = Wwf + (size_t)myvt * 20480 + lane * 8;
    unsigned epoch = 0;

    u64 R[2][4];
    short8 Bh[3], Bl[3];

#define ISSUE(M)                                                               \
    do {                                                                       \
        const u64* ga_ = (const u64*)(hfb + (size_t)(M) * 16384 +              \
                                      wv * 2048 + lane * 16);                  \
        R[(M) & 1][0] = AL64(ga_ + 0);                                         \
        R[(M) & 1][1] = AL64(ga_ + 1);                                         \
        R[(M) & 1][2] = AL64(ga_ + 128);                                       \
        R[(M) & 1][3] = AL64(ga_ + 129);                                       \
        if (act) {                                                             \
            const unsigned short* bp_ = Bbase + (size_t)(M) * 1024;            \
            Bh[(M) % 3] = ld8(bp_);                                            \
            Bl[(M) % 3] = ld8(bp_ + 512);                                      \
        }                                                                      \
    } while (0)

#define WRA(M)                                                                 \
    do {                                                                       \
        u64* da_ = (u64*)(sA[(M) % 3] + wv * 2048 + lane * 16);                \
        da_[0] = R[(M) & 1][0];                                                \
        da_[1] = R[(M) & 1][1];                                                \
        da_[128] = R[(M) & 1][2];                                              \
        da_[129] = R[(M) & 1][3];                                              \
    } while (0)

#define LSTEP(K)                                                               \
    do {                                                                       \
        if ((K) + 2 < 20) ISSUE((K) + 2);                                      \
        if ((K) <= 17) { if (act) { VMW(6); } else { VMW(4); } }               \
        else { VMW(0); }                                                       \
        if ((K) + 1 < 20) WRA((K) + 1);                                        \
        asm volatile("s_waitcnt lgkmcnt(0)" ::: "memory");                     \
        __builtin_amdgcn_s_barrier();                                          \
        __builtin_amdgcn_sched_barrier(0);                                     \
        if (act) {                                                             \
            const unsigned short* ab_ = (const unsigned short*)sA[(K) % 3];    \
            _Pragma("unroll")                                                  \
            for (int mt = 0; mt < 8; ++mt) {                                   \
                short8 ah_ = ld8(ab_ + mt * 1024 + lane * 8);                  \
                short8 al_ = ld8(ab_ + mt * 1024 + 512 + lane * 8);            \
                acc[mt] = MFMA(ah_, Bh[(K) % 3], acc[mt]);                     \
                acc[mt] = MFMA(ah_, Bl[(K) % 3], acc[mt]);                     \
                acc[mt] = MFMA(al_, Bh[(K) % 3], acc[mt]);                     \
            }                                                                  \
        }                                                                      \
    } while (0)

    for (int t = 0; t < TMAX; ++t) {
        // ---------- G: gates + activation -> hf (block-local vt) ----------
        if (gact) {
            const int g_vt = bid;              // 0..38
            const int g_mt = wv;               // 0..7
            f32x4 aI = (f32x4)0.f, aG = (f32x4)0.f, aO = (f32x4)0.f;
            if (t > 0) {
                int n = g_mt * 16 + (lane & 15);
                u64 s = AL64(&slots[(size_t)(t - 1) * NSEQ + n]);
                unsigned idx = 0xFFFFFFFFu - (unsigned)(s & 0xFFFFFFFFull);
                const unsigned short* eh = embhi + (size_t)idx * 640 + ((lane >> 4) << 3);
                const unsigned short* el = emblo + (size_t)idx * 640 + ((lane >> 4) << 3);
                const unsigned short* bI = Wgf3 + (size_t)(0 * 39 + g_vt) * 20480 + lane * 8;
                const unsigned short* bG = Wgf3 + (size_t)(1 * 39 + g_vt) * 20480 + lane * 8;
                const unsigned short* bO = Wgf3 + (size_t)(2 * 39 + g_vt) * 20480 + lane * 8;
#pragma unroll 2
                for (int ks = 0; ks < 20; ++ks) {
                    short8 ah = ld8(eh + ks * 32);
                    short8 al = ld8(el + ks * 32);
                    short8 bIh = ld8(bI), bIl = ld8(bI + 512);
                    short8 bGh = ld8(bG), bGl = ld8(bG + 512);
                    short8 bOh = ld8(bO), bOl = ld8(bO + 512);
                    aI = MFMA(ah, bIh, aI); aI = MFMA(ah, bIl, aI); aI = MFMA(al, bIh, aI);
                    aG = MFMA(ah, bGh, aG); aG = MFMA(ah, bGl, aG); aG = MFMA(al, bGh, aG);
                    aO = MFMA(ah, bOh, aO); aO = MFMA(ah, bOl, aO); aO = MFMA(al, bOh, aO);
                    bI += 1024; bG += 1024; bO += 1024;
                }
            }
            int col = g_vt * 16 + (lane & 15);
            if (col < WORD) {
                int rbase = g_mt * 16 + ((lane >> 4) << 2);
#pragma unroll
                for (int r = 0; r < 4; ++r) {
                    int n = rbase + r;
                    float gi = aI[r] + base[(size_t)n * 1872 + col];
                    float gg = aG[r] + base[(size_t)n * 1872 + 620 + col];
                    float go = aO[r] + base[(size_t)n * 1872 + 1240 + col];
                    float si = 1.f / (1.f + expf(-gi));
                    float so = 1.f / (1.f + expf(-go));
                    float h = so * tanhf(si * tanhf(gg));
                    int pos = (((col >> 5) * 8 + (n >> 4)) * 1024) +
                              (((n & 15) + (((col & 31) >> 3) << 4)) * 8) + (col & 7);
                    unsigned short hi = bf16rne(h);
                    hf[pos] = hi;
                    hf[pos + 512] = bf16rne(h - bf16tof(hi));
                }
            }
        }
        if (tid < 128) keybuf[tid] = 0ull;
        ++epoch;
        gridbar(bar, epoch, gact);          // hf in IC (G-blocks released)

        // ---------- L: B in reg double-buffer, A reg-staged via 3 LDS bufs ----------
        f32x4 acc[8];
#pragma unroll
        for (int mt = 0; mt < 8; ++mt) acc[mt] = (f32x4)0.f;

        ISSUE(0);
        ISSUE(1);
        if (act) { VMW(6); } else { VMW(4); }
        WRA(0);

        LSTEP(0);  LSTEP(1);  LSTEP(2);  LSTEP(3);  LSTEP(4);
        LSTEP(5);  LSTEP(6);  LSTEP(7);  LSTEP(8);  LSTEP(9);
        LSTEP(10); LSTEP(11); LSTEP(12); LSTEP(13); LSTEP(14);
        LSTEP(15); LSTEP(16); LSTEP(17); LSTEP(18); LSTEP(19);

        int q = lane >> 4, cof = lane & 15;
        if (act) {
            int v = myvt * 16 + cof;
            float bwv = bw[v];
#pragma unroll
            for (int mt = 0; mt < 8; ++mt) {
#pragma unroll
                for (int r = 0; r < 4; ++r) {
                    int n = mt * 16 + q * 4 + r;
                    float x = acc[mt][r] + bwv;
                    out[((size_t)n * TMAX + t) * VOCAB + v] = x;
                    u64 key = ((u64)ford(x) << 32) | (u64)(0xFFFFFFFFu - (unsigned)v);
#pragma unroll
                    for (int s2 = 1; s2 <= 8; s2 <<= 1) {
                        u64 o = __shfl_xor(key, s2, 64);
                        if (o > key) key = o;
                    }
                    if (cof == 0) atomicMax(&keybuf[n], key);
                }
            }
        }
        __syncthreads();
        if (tid < 128) {
            u64 k = keybuf[tid];
            if (k) atomicMax(&slots[(size_t)t * NSEQ + tid], k);
        }
        if (t + 1 < TMAX) {
            ++epoch;
            gridbar(bar, epoch, false);     // slots visible via IC atomics
        }
    }
#undef LSTEP
#undef WRA
#undef ISSUE
}

// =====================================================================
// fallback (round-2 proven path) — used only if ws too small for mega
// =====================================================================
__global__ __launch_bounds__(256) void kinit2(unsigned int* lastfrag32,
                                              unsigned int* hfrag32,
                                              unsigned int* slots32,
                                              float* bsum,
                                              const float* __restrict__ b_ih,
                                              const float* __restrict__ b_hh) {
    int i = blockIdx.x * 256 + threadIdx.x;
    if (i < 81920) { lastfrag32[i] = 0u; hfrag32[i] = 0u; }
    if (i < 7680) slots32[i] = 0u;
    if (i < 1872) {
        float v = 0.f;
        if (i < 1860) {
            int row = (i < 620) ? i : i + 620;
            v = b_ih[row] + b_hh[row];
        }
        bsum[i] = v;
    }
}

__global__ __launch_bounds__(256) void klogits2(const unsigned short* __restrict__ Hf,
                                                const unsigned short* __restrict__ Wf,
                                                const float* __restrict__ bw,
                                                float* __restrict__ out,
                                                u64* __restrict__ slots, int t) {
    __shared__ u64 keybuf[128];
    int tid = threadIdx.x;
    if (tid < 128) keybuf[tid] = 0ull;
    __syncthreads();
    int lane = tid & 63, wv = tid >> 6;
    int vtb = blockIdx.x * 8 + wv * 2;
    bool ok0 = vtb < 1250, ok1 = (vtb + 1) < 1250;
    f32x4 acc[8][2];
#pragma unroll
    for (int m = 0; m < 8; ++m) { acc[m][0] = (f32x4)0.f; acc[m][1] = (f32x4)0.f; }
    if (ok0) {
        const unsigned short* ap = Hf + lane * 8;
        const unsigned short* bp0 = Wf + (size_t)vtb * 20 * 1024 + lane * 8;
        const unsigned short* bp1 = bp0 + 20 * 1024;
#pragma unroll 2
        for (int ks = 0; ks < 20; ++ks) {
            short8 b0h = ld8(bp0), b0l = ld8(bp0 + 512);
            short8 ah[8], al[8];
#pragma unroll
            for (int m = 0; m < 8; ++m) {
                ah[m] = ld8(ap + m * 1024);
                al[m] = ld8(ap + m * 1024 + 512);
            }
#pragma unroll
            for (int m = 0; m < 8; ++m) {
                acc[m][0] = MFMA(ah[m], b0h, acc[m][0]);
                acc[m][0] = MFMA(ah[m], b0l, acc[m][0]);
                acc[m][0] = MFMA(al[m], b0h, acc[m][0]);
            }
            if (ok1) {
                short8 b1h = ld8(bp1), b1l = ld8(bp1 + 512);
#pragma unroll
                for (int m = 0; m < 8; ++m) {
                    acc[m][1] = MFMA(ah[m], b1h, acc[m][1]);
                    acc[m][1] = MFMA(ah[m], b1l, acc[m][1]);
                    acc[m][1] = MFMA(al[m], b1h, acc[m][1]);
                }
            }
            ap += 8192; bp0 += 1024; bp1 += 1024;
        }
    }
    int rbase = (lane >> 4) << 2;
    int cof = lane & 15;
    float bw0 = ok0 ? bw[vtb * 16 + cof] : 0.f;
    float bw1 = ok1 ? bw[(vtb + 1) * 16 + cof] : 0.f;
#pragma unroll
    for (int m = 0; m < 8; ++m) {
#pragma unroll
        for (int r = 0; r < 4; ++r) {
            int row = m * 16 + rbase + r;
            u64 km = 0ull;
            if (ok0) {
                int v = vtb * 16 + cof;
                float x = acc[m][0][r] + bw0;
                out[((size_t)row * TMAX + t) * VOCAB + v] = x;
                km = ((u64)ford(x) << 32) | (u64)(0xFFFFFFFFu - (unsigned)v);
            }
            if (ok1) {
                int v = (vtb + 1) * 16 + cof;
                float x = acc[m][1][r] + bw1;
                out[((size_t)row * TMAX + t) * VOCAB + v] = x;
                u64 k2 = ((u64)ford(x) << 32) | (u64)(0xFFFFFFFFu - (unsigned)v);
                if (k2 > km) km = k2;
            }
#pragma unroll
            for (int s2 = 1; s2 <= 8; s2 <<= 1) {
                u64 o = __shfl_xor(km, s2, 64);
                if (o > km) km = o;
            }
            if ((lane & 15) == 0 && km) atomicMax(&keybuf[row], km);
        }
    }
    __syncthreads();
    if (tid < 128) atomicMax(&slots[(size_t)t * NSEQ + tid], keybuf[tid]);
}

__global__ void kact(const float* __restrict__ gates,
                     unsigned short* __restrict__ hfrag) {
    int n = blockIdx.x;
    int k = threadIdx.x;
    if (k >= WORD) return;
    const float* g = gates + (size_t)n * 1872;
    float gi = g[k], gg = g[620 + k], go = g[1240 + k];
    float si = 1.f / (1.f + expf(-gi));
    float so = 1.f / (1.f + expf(-go));
    float h = so * tanhf(si * tanhf(gg));
    int ks = k >> 5, mt = n >> 4;
    int lane = (n & 15) + (((k & 31) >> 3) << 4);
    int j = k & 7;
    size_t ob = (size_t)(ks * 8 + mt) * 1024 + lane * 8 + j;
    unsigned short hi = bf16rne(h);
    hfrag[ob] = hi;
    hfrag[ob + 512] = bf16rne(h - bf16tof(hi));
}

__global__ void kgather2(const float* __restrict__ embed,
                         const u64* __restrict__ slots,
                         unsigned short* __restrict__ lastfrag, int t) {
    int n = blockIdx.x;
    int k = threadIdx.x;
    if (k >= WORD) return;
    u64 s = slots[(size_t)t * NSEQ + n];
    unsigned idx = 0xFFFFFFFFu - (unsigned)(s & 0xFFFFFFFFull);
    float x = embed[(size_t)idx * WORD + k];
    int ks = k >> 5, mt = n >> 4;
    int lane = (n & 15) + (((k & 31) >> 3) << 4);
    int j = k & 7;
    size_t ob = (size_t)(ks * 8 + mt) * 1024 + lane * 8 + j;
    unsigned short hi = bf16rne(x);
    lastfrag[ob] = hi;
    lastfrag[ob + 512] = bf16rne(x - bf16tof(hi));
}

// =====================================================================
extern "C" void kernel_launch(void* const* d_in, const int* in_sizes, int n_in,
                              void* d_out, int out_size, void* d_ws, size_t ws_size,
                              hipStream_t stream) {
    const float* thoughts = (const float*)d_in[0];
    const float* embed    = (const float*)d_in[1];
    const float* W_ih     = (const float*)d_in[2];
    // d_in[3] = W_hh: dead (h0 == 0 always)
    const float* b_ih     = (const float*)d_in[4];
    const float* b_hh     = (const float*)d_in[5];
    const float* Ww       = (const float*)d_in[6];
    const float* bw       = (const float*)d_in[7];
    float* out = (float*)d_out;
    char* ws = (char*)d_ws;

    // mega layout
    const size_t OFF_WWF  = 0;              // 51,200,000
    const size_t OFF_WBF  = 51200000;       // 17,971,200
    const size_t OFF_WGF3 = 69171200;       //  4,792,320
    const size_t OFF_CTXF = 73963520;       //  1,228,800
    const size_t OFF_EHI  = 75192320;       // 25,600,000
    const size_t OFF_ELO  = 100792320;      // 25,600,000
    const size_t OFF_HF   = 126392320;      //    327,680
    const size_t OFF_BASE = 126720000;      //    958,464
    const size_t OFF_BSUM = 127678464;      //      7,488
    const size_t OFF_SLOT = 127685952;      //     30,720
    const size_t OFF_BAR  = 127716672;      //      2,048
    const size_t NEED_MEGA = 127718720;

    if (ws_size >= NEED_MEGA) {
        unsigned short* Wwf  = (unsigned short*)(ws + OFF_WWF);
        unsigned short* Wbf  = (unsigned short*)(ws + OFF_WBF);
        unsigned short* Wgf3 = (unsigned short*)(ws + OFF_WGF3);
        unsigned short* ctxf = (unsigned short*)(ws + OFF_CTXF);
        unsigned short* ehi  = (unsigned short*)(ws + OFF_EHI);
        unsigned short* elo  = (unsigned short*)(ws + OFF_ELO);
        unsigned short* hf   = (unsigned short*)(ws + OFF_HF);
        float* base = (float*)(ws + OFF_BASE);
        float* bsum = (float*)(ws + OFF_BSUM);
        u64*   slots = (u64*)(ws + OFF_SLOT);
        unsigned* bar = (unsigned*)(ws + OFF_BAR);

        kinit3<<<320, 256, 0, stream>>>((unsigned*)hf, (unsigned*)slots, bsum, bar, b_ih, b_hh);
        kpack_w<<<50000, 256, 0, stream>>>(Ww, Wwf, 1250, 20, 0, 620, WORD, VOCAB, 0);
        kpack_w<<<17550, 256, 0, stream>>>(W_ih, Wbf, 117, 75, 0, 2400, XK, 1860, 1);
        kpack_w<<<1560, 256, 0, stream>>>(W_ih + (size_t)0 * XK,    Wgf3 + 0 * 798720, 39, 20, 2400, 620, XK, 620, 0);
        kpack_w<<<1560, 256, 0, stream>>>(W_ih + (size_t)1240 * XK, Wgf3 + 1 * 798720, 39, 20, 2400, 620, XK, 620, 0);
        kpack_w<<<1560, 256, 0, stream>>>(W_ih + (size_t)1860 * XK, Wgf3 + 2 * 798720, 39, 20, 2400, 620, XK, 620, 0);
        kpack_ctx<<<1200, 256, 0, stream>>>(thoughts, ctxf);
        kpack_embed<<<50000, 256, 0, stream>>>(embed, ehi, elo);
        ggemm<<<15, 256, 0, stream>>>(ctxf, Wbf, bsum, nullptr, base, 75, 117, 1872);

        kmega<<<NBLK, 512, 0, stream>>>(ehi, elo, Wgf3, Wwf, base, bw, hf, slots, out, bar);
    } else {
        // round-2 fallback layout
        const size_t F_WWF  = 0;
        const size_t F_WBF  = 51200000;
        const size_t F_WGF  = 69171200;
        const size_t F_CTXF = 73963520;
        const size_t F_HF   = 75192320;
        const size_t F_LF   = 75520000;
        const size_t F_BASE = 75847680;
        const size_t F_GATE = 76806144;
        const size_t F_BSUM = 77764608;
        const size_t F_SLOT = 77772096;

        unsigned short* Wwf  = (unsigned short*)(ws + F_WWF);
        unsigned short* Wbf  = (unsigned short*)(ws + F_WBF);
        unsigned short* Wgf  = (unsigned short*)(ws + F_WGF);
        unsigned short* ctxf = (unsigned short*)(ws + F_CTXF);
        unsigned short* hf   = (unsigned short*)(ws + F_HF);
        unsigned short* lf   = (unsigned short*)(ws + F_LF);
        float* base = (float*)(ws + F_BASE);
        float* gate = (float*)(ws + F_GATE);
        float* bsum = (float*)(ws + F_BSUM);
        u64*   slots = (u64*)(ws + F_SLOT);

        kinit2<<<320, 256, 0, stream>>>((unsigned int*)lf, (unsigned int*)hf,
                                        (unsigned int*)slots, bsum, b_ih, b_hh);
        kpack_w<<<50000, 256, 0, stream>>>(Ww, Wwf, 1250, 20, 0, 620, WORD, VOCAB, 0);
        kpack_w<<<17550, 256, 0, stream>>>(W_ih, Wbf, 117, 75, 0, 2400, XK, 1860, 1);
        kpack_w<<<4680, 256, 0, stream>>>(W_ih, Wgf, 117, 20, 2400, 620, XK, 1860, 1);
        kpack_ctx<<<1200, 256, 0, stream>>>(thoughts, ctxf);
        ggemm<<<15, 256, 0, stream>>>(ctxf, Wbf, bsum, nullptr, base, 75, 117, 1872);
        for (int t = 0; t < TMAX; ++t) {
            ggemm<<<15, 256, 0, stream>>>(lf, Wgf, nullptr, base, gate, 20, 117, 1872);
            kact<<<NSEQ, 640, 0, stream>>>(gate, hf);
            klogits2<<<157, 256, 0, stream>>>(hf, Wwf, bw, out, slots, t);
            if (t + 1 < TMAX)
                kgather2<<<NSEQ, 640, 0, stream>>>(embed, slots, lf, t);
        }
    }
}

// Round 14
// 1526.828 us; speedup vs baseline: 1.6109x; 1.1597x over previous
//
#include <hip/hip_runtime.h>
#include <math.h>

#define VOCAB 20000
#define WORD 620
#define NSEQ 128
#define TMAX 30
#define CTXK 2400
#define XK 3020
#define NBLK 256

typedef unsigned long long u64;
typedef __attribute__((ext_vector_type(8))) short short8;
typedef __attribute__((ext_vector_type(4))) float f32x4;

// ---------- helpers ----------
__device__ __forceinline__ unsigned ford(float f) {
    unsigned b = __float_as_uint(f);
    return (b & 0x80000000u) ? ~b : (b | 0x80000000u);
}
__device__ __forceinline__ unsigned short bf16rne(float x) {
    unsigned u = __float_as_uint(x);
    return (unsigned short)((u + 0x7fffu + ((u >> 16) & 1u)) >> 16);
}
__device__ __forceinline__ float bf16tof(unsigned short h) {
    return __uint_as_float(((unsigned)h) << 16);
}
__device__ __forceinline__ short8 ld8(const unsigned short* p) {
    return *(const short8*)p;
}
#define MFMA(a, b, c) __builtin_amdgcn_mfma_f32_16x16x32_bf16((a), (b), (c), 0, 0, 0)
#define VMW(N) asm volatile("s_waitcnt vmcnt(" #N ")" ::: "memory")
#define AL64(p) __hip_atomic_load((p), __ATOMIC_RELAXED, __HIP_MEMORY_SCOPE_AGENT)

// async 16B/lane global->LDS copy; LDS dest = uniform base + lane*16
__device__ __forceinline__ void gload_lds16(const void* g, void* l) {
    __builtin_amdgcn_global_load_lds((const __attribute__((address_space(1))) void*)g,
                                     (__attribute__((address_space(3))) void*)l,
                                     16, 0, 0);
}

// Grid barrier v4 (round-13 proven): 16 group counters on separate cache
// lines + root; RELAXED spin; NO acquire fence (cross-step data read via
// agent-scope atomics); release fence only on G-blocks.
__device__ __forceinline__ void gridbar(unsigned* bar, unsigned epoch, bool rel) {
    __syncthreads();
    if (threadIdx.x == 0) {
        if (rel) __threadfence();       // wbl2: push dirty hf lines to IC
        unsigned g = blockIdx.x >> 4;
        unsigned a = __hip_atomic_fetch_add(&bar[g * 16], 1u, __ATOMIC_RELAXED, __HIP_MEMORY_SCOPE_AGENT);
        if (a == epoch * 16u - 1u)
            __hip_atomic_fetch_add(&bar[256], 1u, __ATOMIC_RELAXED, __HIP_MEMORY_SCOPE_AGENT);
        while (__hip_atomic_load(&bar[256], __ATOMIC_RELAXED, __HIP_MEMORY_SCOPE_AGENT) < epoch * 16u)
            __builtin_amdgcn_s_sleep(2);
    }
    __syncthreads();
}

// =====================================================================
// Shared fragment layout (m91-verified trio), all buffers [tile][ks][2][64][8]:
//   A frag: lane holds A[row = mt*16 + lane%16][k = ks*32 + (lane/16)*8 + j]
//   B frag: lane holds B[col = vt*16 + lane%16][k = ...same...]
//   C/D:    row = (lane>>4)*4 + r, col = lane&15
// =====================================================================

__global__ __launch_bounds__(256) void kpack_w(const float* __restrict__ src,
                                               unsigned short* __restrict__ dst,
                                               int nvt, int nks, int col0,
                                               int ncols_valid, int src_ld,
                                               int nrows_valid, int rowmap) {
    int i = blockIdx.x * 256 + threadIdx.x;
    if (i >= nvt * nks * 512) return;
    int j = i & 7;
    int lane = (i >> 3) & 63;
    int t2 = i >> 9;
    int ks = t2 % nks;
    int vt = t2 / nks;
    int r = vt * 16 + (lane & 15);
    int k = ks * 32 + ((lane >> 4) << 3) + j;
    float x = 0.f;
    if (r < nrows_valid && k < ncols_valid) {
        int row = (rowmap == 1) ? ((r < 620) ? r : r + 620) : r;
        x = src[(size_t)row * src_ld + col0 + k];
    }
    unsigned short hi = bf16rne(x);
    unsigned short lo = bf16rne(x - bf16tof(hi));
    size_t ob = (size_t)t2 * 1024 + lane * 8 + j;
    dst[ob] = hi;
    dst[ob + 512] = lo;
}

__global__ __launch_bounds__(256) void kpack_ctx(const float* __restrict__ th,
                                                 unsigned short* __restrict__ dst) {
    int i = blockIdx.x * 256 + threadIdx.x;
    if (i >= 75 * 8 * 512) return;
    int j = i & 7;
    int lane = (i >> 3) & 63;
    int t2 = i >> 9;
    int mt = t2 & 7;
    int ks = t2 >> 3;
    int n = mt * 16 + (lane & 15);
    int k = ks * 32 + ((lane >> 4) << 3) + j;
    float x = (k < 1200) ? th[(size_t)n * 1200 + k]
                         : th[(size_t)(n + 2) * 1200 + (k - 1200)];
    unsigned short hi = bf16rne(x);
    unsigned short lo = bf16rne(x - bf16tof(hi));
    size_t ob = (size_t)t2 * 1024 + lane * 8 + j;
    dst[ob] = hi;
    dst[ob + 512] = lo;
}

__global__ __launch_bounds__(256) void kpack_embed(const float* __restrict__ embed,
                                                   unsigned short* __restrict__ ehi,
                                                   unsigned short* __restrict__ elo) {
    size_t i = (size_t)blockIdx.x * 256 + threadIdx.x;
    if (i >= (size_t)VOCAB * 640) return;
    int v = (int)(i / 640);
    int k = (int)(i % 640);
    float x = (k < WORD) ? embed[(size_t)v * WORD + k] : 0.f;
    unsigned short hi = bf16rne(x);
    ehi[i] = hi;
    elo[i] = bf16rne(x - bf16tof(hi));
}

// generic frag GEMM (setup only): outT[row][col] = A@B^T (+addRow)
__global__ __launch_bounds__(256) void ggemm(const unsigned short* __restrict__ Af,
                                             const unsigned short* __restrict__ Bf,
                                             const float* __restrict__ addRow,
                                             const float* __restrict__ addFull,
                                             float* __restrict__ outT,
                                             int nks, int nvt, int ldout) {
    int lane = threadIdx.x & 63, wv = threadIdx.x >> 6;
    int vtb = blockIdx.x * 8 + wv * 2;
    bool ok0 = vtb < nvt, ok1 = (vtb + 1) < nvt;
    f32x4 acc[8][2];
#pragma unroll
    for (int m = 0; m < 8; ++m) { acc[m][0] = (f32x4)0.f; acc[m][1] = (f32x4)0.f; }
    if (ok0) {
        const unsigned short* ap = Af + lane * 8;
        const unsigned short* bp0 = Bf + (size_t)vtb * nks * 1024 + lane * 8;
        const unsigned short* bp1 = bp0 + (size_t)nks * 1024;
        for (int ks = 0; ks < nks; ++ks) {
            short8 b0h = ld8(bp0), b0l = ld8(bp0 + 512);
            short8 ah[8], al[8];
#pragma unroll
            for (int m = 0; m < 8; ++m) {
                ah[m] = ld8(ap + m * 1024);
                al[m] = ld8(ap + m * 1024 + 512);
            }
#pragma unroll
            for (int m = 0; m < 8; ++m) {
                acc[m][0] = MFMA(ah[m], b0h, acc[m][0]);
                acc[m][0] = MFMA(ah[m], b0l, acc[m][0]);
                acc[m][0] = MFMA(al[m], b0h, acc[m][0]);
            }
            if (ok1) {
                short8 b1h = ld8(bp1), b1l = ld8(bp1 + 512);
#pragma unroll
                for (int m = 0; m < 8; ++m) {
                    acc[m][1] = MFMA(ah[m], b1h, acc[m][1]);
                    acc[m][1] = MFMA(ah[m], b1l, acc[m][1]);
                    acc[m][1] = MFMA(al[m], b1h, acc[m][1]);
                }
            }
            ap += 8192; bp0 += 1024; bp1 += 1024;
        }
    }
    int rbase = (lane >> 4) << 2;
    int cof = lane & 15;
#pragma unroll
    for (int v = 0; v < 2; ++v) {
        bool ok = v ? ok1 : ok0;
        if (!ok) continue;
        int col = (vtb + v) * 16 + cof;
        float ar = addRow ? addRow[col] : 0.f;
#pragma unroll
        for (int m = 0; m < 8; ++m) {
#pragma unroll
            for (int r = 0; r < 4; ++r) {
                int row = m * 16 + rbase + r;
                float x = acc[m][v][r] + ar;
                if (addFull) x += addFull[(size_t)row * ldout + col];
                outT[(size_t)row * ldout + col] = x;
            }
        }
    }
}

// init for mega path
__global__ __launch_bounds__(256) void kinit3(unsigned* hf32, unsigned* slots32,
                                              float* bsum, unsigned* bar,
                                              const float* __restrict__ b_ih,
                                              const float* __restrict__ b_hh) {
    int i = blockIdx.x * 256 + threadIdx.x;
    if (i < 81920) hf32[i] = 0u;
    if (i < 7680) slots32[i] = 0u;
    if (i < 512) bar[i] = 0u;
    if (i < 1872) {
        float v = 0.f;
        if (i < 1860) {
            int row = (i < 620) ? i : i + 620;   // [i, g, o] -> W_ih rows
            v = b_ih[row] + b_hh[row];
        }
        bsum[i] = v;
    }
}

// =====================================================================
// Persistent decode kernel v11: B-hi RESIDENT IN LDS (staged once via
// gload_lds16, <=100 KB/block) -> half the Ww stream costs zero bytes
// per step and is immune to cache traffic. B-lo (3.2 MB/XCD) via normal
// loads -> L2-resident. A(hf) reg-staged depth-4 via agent atomics into
// 3 LDS buffers; nt out stores keep L2 clean. Fence-free barrier
// (round-13). Math bit-identical (same 3-MFMA split-bf16, ks ascending).
// LDS: 100K (Bhi) + 48K (A bufs) + 1K (keybuf) = 152.6 KB < 160 KB.
// =====================================================================
__global__ __launch_bounds__(512, 2) void kmega(
    const unsigned short* __restrict__ embhi,
    const unsigned short* __restrict__ emblo,
    const unsigned short* __restrict__ Wgf3,
    const unsigned short* __restrict__ Wwf,
    const float* __restrict__ base,
    const float* __restrict__ bw,
    unsigned short* __restrict__ hf,
    u64* __restrict__ slots,
    float* __restrict__ out,
    unsigned* bar) {
    __shared__ char sBhi[102400];              // [vt_local][ks][1024B]
    __shared__ char sA[3][16384];
    __shared__ u64 keybuf[128];
    const int tid = threadIdx.x;
    const int lane = tid & 63;
    const int wv = tid >> 6;                   // 0..7
    const int bid = blockIdx.x;

    const int vt_lo = (int)(((long long)bid * 1250) / NBLK);
    const int vt_hi = (int)(((long long)(bid + 1) * 1250) / NBLK);
    const int nvt = vt_hi - vt_lo;             // 4 or 5
    const bool act = (wv < nvt);               // wave owns one vt
    const int myvt = vt_lo + (act ? wv : 0);
    const bool gact = (bid < 39);              // block owns G-vt = bid, wave = mt

    const char* hfb = (const char*)hf;
    const char* wwb = (const char*)Wwf;
    // lo-halves: shorts at (vt*20+ks)*1024 + 512  ->  bytes vt*40960+ks*2048+1024
    const unsigned short* BbaseLo = Wwf + (size_t)myvt * 20480 + 512 + lane * 8;
    unsigned epoch = 0;

    // ---- one-time: stage B-hi (nvt*20 lines of 1 KB) into LDS ----
    for (int i = wv; i < nvt * 20; i += 8) {
        const char* g = wwb + (size_t)(vt_lo + i / 20) * 40960 + (size_t)(i % 20) * 2048 + lane * 16;
        gload_lds16(g, sBhi + (size_t)i * 1024);
    }
    VMW(0);
    __syncthreads();

    u64 R[3][4];
    short8 Bl[4];

#define ISSUE(M)                                                               \
    do {                                                                       \
        const u64* ga_ = (const u64*)(hfb + (size_t)(M) * 16384 +              \
                                      wv * 2048 + lane * 16);                  \
        R[(M) % 3][0] = AL64(ga_ + 0);                                         \
        R[(M) % 3][1] = AL64(ga_ + 1);                                         \
        R[(M) % 3][2] = AL64(ga_ + 128);                                       \
        R[(M) % 3][3] = AL64(ga_ + 129);                                       \
        if (act) Bl[(M) % 4] = ld8(BbaseLo + (size_t)(M) * 1024);              \
    } while (0)

#define WRA(M)                                                                 \
    do {                                                                       \
        u64* da_ = (u64*)(sA[(M) % 3] + wv * 2048 + lane * 16);                \
        da_[0] = R[(M) % 3][0];                                                \
        da_[1] = R[(M) % 3][1];                                                \
        da_[128] = R[(M) % 3][2];                                              \
        da_[129] = R[(M) % 3][3];                                              \
    } while (0)

// per-chunk per-wave vmem ops: act ? 5 : 4 (4 A atomics + 1 B-lo load)
#define LSTEP(K)                                                               \
    do {                                                                       \
        if ((K) + 3 < 20) ISSUE((K) + 3);                                      \
        if ((K) <= 16) { if (act) { VMW(10); } else { VMW(8); } }              \
        else if ((K) == 17) { if (act) { VMW(5); } else { VMW(4); } }          \
        else { VMW(0); }                                                       \
        if ((K) + 1 < 20) WRA((K) + 1);                                        \
        asm volatile("s_waitcnt lgkmcnt(0)" ::: "memory");                     \
        __builtin_amdgcn_s_barrier();                                          \
        __builtin_amdgcn_sched_barrier(0);                                     \
        if (act) {                                                             \
            const unsigned short* ab_ = (const unsigned short*)sA[(K) % 3];    \
            short8 bh_ = ld8((const unsigned short*)(sBhi +                    \
                             (size_t)(wv * 20 + (K)) * 1024) + lane * 8);      \
            _Pragma("unroll")                                                  \
            for (int mt = 0; mt < 8; ++mt) {                                   \
                short8 ah_ = ld8(ab_ + mt * 1024 + lane * 8);                  \
                short8 al_ = ld8(ab_ + mt * 1024 + 512 + lane * 8);            \
                acc[mt] = MFMA(ah_, bh_, acc[mt]);                             \
                acc[mt] = MFMA(ah_, Bl[(K) % 4], acc[mt]);                     \
                acc[mt] = MFMA(al_, bh_, acc[mt]);                             \
            }                                                                  \
        }                                                                      \
    } while (0)

    for (int t = 0; t < TMAX; ++t) {
        // ---------- G: gates + activation -> hf (block-local vt) ----------
        if (gact) {
            const int g_vt = bid;              // 0..38
            const int g_mt = wv;               // 0..7
            f32x4 aI = (f32x4)0.f, aG = (f32x4)0.f, aO = (f32x4)0.f;
            if (t > 0) {
                int n = g_mt * 16 + (lane & 15);
                u64 s = AL64(&slots[(size_t)(t - 1) * NSEQ + n]);
                unsigned idx = 0xFFFFFFFFu - (unsigned)(s & 0xFFFFFFFFull);
                const unsigned short* eh = embhi + (size_t)idx * 640 + ((lane >> 4) << 3);
                const unsigned short* el = emblo + (size_t)idx * 640 + ((lane >> 4) << 3);
                const unsigned short* bI = Wgf3 + (size_t)(0 * 39 + g_vt) * 20480 + lane * 8;
                const unsigned short* bG = Wgf3 + (size_t)(1 * 39 + g_vt) * 20480 + lane * 8;
                const unsigned short* bO = Wgf3 + (size_t)(2 * 39 + g_vt) * 20480 + lane * 8;
#pragma unroll 2
                for (int ks = 0; ks < 20; ++ks) {
                    short8 ah = ld8(eh + ks * 32);
                    short8 al = ld8(el + ks * 32);
                    short8 bIh = ld8(bI), bIl = ld8(bI + 512);
                    short8 bGh = ld8(bG), bGl = ld8(bG + 512);
                    short8 bOh = ld8(bO), bOl = ld8(bO + 512);
                    aI = MFMA(ah, bIh, aI); aI = MFMA(ah, bIl, aI); aI = MFMA(al, bIh, aI);
                    aG = MFMA(ah, bGh, aG); aG = MFMA(ah, bGl, aG); aG = MFMA(al, bGh, aG);
                    aO = MFMA(ah, bOh, aO); aO = MFMA(ah, bOl, aO); aO = MFMA(al, bOh, aO);
                    bI += 1024; bG += 1024; bO += 1024;
                }
            }
            int col = g_vt * 16 + (lane & 15);
            if (col < WORD) {
                int rbase = g_mt * 16 + ((lane >> 4) << 2);
#pragma unroll
                for (int r = 0; r < 4; ++r) {
                    int n = rbase + r;
                    float gi = aI[r] + base[(size_t)n * 1872 + col];
                    float gg = aG[r] + base[(size_t)n * 1872 + 620 + col];
                    float go = aO[r] + base[(size_t)n * 1872 + 1240 + col];
                    float si = 1.f / (1.f + expf(-gi));
                    float so = 1.f / (1.f + expf(-go));
                    float h = so * tanhf(si * tanhf(gg));
                    int pos = (((col >> 5) * 8 + (n >> 4)) * 1024) +
                              (((n & 15) + (((col & 31) >> 3) << 4)) * 8) + (col & 7);
                    unsigned short hi = bf16rne(h);
                    hf[pos] = hi;
                    hf[pos + 512] = bf16rne(h - bf16tof(hi));
                }
            }
        }
        if (tid < 128) keybuf[tid] = 0ull;
        ++epoch;
        gridbar(bar, epoch, gact);          // hf in IC (G-blocks released)

        // ---------- L: B-hi from LDS, B-lo from L2, A depth-4 reg-staged ----------
        f32x4 acc[8];
#pragma unroll
        for (int mt = 0; mt < 8; ++mt) acc[mt] = (f32x4)0.f;

        ISSUE(0);
        ISSUE(1);
        ISSUE(2);
        if (act) { VMW(10); } else { VMW(8); }
        WRA(0);

        LSTEP(0);  LSTEP(1);  LSTEP(2);  LSTEP(3);  LSTEP(4);
        LSTEP(5);  LSTEP(6);  LSTEP(7);  LSTEP(8);  LSTEP(9);
        LSTEP(10); LSTEP(11); LSTEP(12); LSTEP(13); LSTEP(14);
        LSTEP(15); LSTEP(16); LSTEP(17); LSTEP(18); LSTEP(19);

        int q = lane >> 4, cof = lane & 15;
        if (act) {
            int v = myvt * 16 + cof;
            float bwv = bw[v];
#pragma unroll
            for (int mt = 0; mt < 8; ++mt) {
#pragma unroll
                for (int r = 0; r < 4; ++r) {
                    int n = mt * 16 + q * 4 + r;
                    float x = acc[mt][r] + bwv;
                    __builtin_nontemporal_store(x, &out[((size_t)n * TMAX + t) * VOCAB + v]);
                    u64 key = ((u64)ford(x) << 32) | (u64)(0xFFFFFFFFu - (unsigned)v);
#pragma unroll
                    for (int s2 = 1; s2 <= 8; s2 <<= 1) {
                        u64 o = __shfl_xor(key, s2, 64);
                        if (o > key) key = o;
                    }
                    if (cof == 0) atomicMax(&keybuf[n], key);
                }
            }
        }
        __syncthreads();
        if (tid < 128) {
            u64 k = keybuf[tid];
            if (k) atomicMax(&slots[(size_t)t * NSEQ + tid], k);
        }
        if (t + 1 < TMAX) {
            ++epoch;
            gridbar(bar, epoch, false);     // slots visible via IC atomics
        }
    }
#undef LSTEP
#undef WRA
#undef ISSUE
}

// =====================================================================
// fallback (round-2 proven path) — used only if ws too small for mega
// =====================================================================
__global__ __launch_bounds__(256) void kinit2(unsigned int* lastfrag32,
                                              unsigned int* hfrag32,
                                              unsigned int* slots32,
                                              float* bsum,
                                              const float* __restrict__ b_ih,
                                              const float* __restrict__ b_hh) {
    int i = blockIdx.x * 256 + threadIdx.x;
    if (i < 81920) { lastfrag32[i] = 0u; hfrag32[i] = 0u; }
    if (i < 7680) slots32[i] = 0u;
    if (i < 1872) {
        float v = 0.f;
        if (i < 1860) {
            int row = (i < 620) ? i : i + 620;
            v = b_ih[row] + b_hh[row];
        }
        bsum[i] = v;
    }
}

__global__ __launch_bounds__(256) void klogits2(const unsigned short* __restrict__ Hf,
                                                const unsigned short* __restrict__ Wf,
                                                const float* __restrict__ bw,
                                                float* __restrict__ out,
                                                u64* __restrict__ slots, int t) {
    __shared__ u64 keybuf[128];
    int tid = threadIdx.x;
    if (tid < 128) keybuf[tid] = 0ull;
    __syncthreads();
    int lane = tid & 63, wv = tid >> 6;
    int vtb = blockIdx.x * 8 + wv * 2;
    bool ok0 = vtb < 1250, ok1 = (vtb + 1) < 1250;
    f32x4 acc[8][2];
#pragma unroll
    for (int m = 0; m < 8; ++m) { acc[m][0] = (f32x4)0.f; acc[m][1] = (f32x4)0.f; }
    if (ok0) {
        const unsigned short* ap = Hf + lane * 8;
        const unsigned short* bp0 = Wf + (size_t)vtb * 20 * 1024 + lane * 8;
        const unsigned short* bp1 = bp0 + 20 * 1024;
#pragma unroll 2
        for (int ks = 0; ks < 20; ++ks) {
            short8 b0h = ld8(bp0), b0l = ld8(bp0 + 512);
            short8 ah[8], al[8];
#pragma unroll
            for (int m = 0; m < 8; ++m) {
                ah[m] = ld8(ap + m * 1024);
                al[m] = ld8(ap + m * 1024 + 512);
            }
#pragma unroll
            for (int m = 0; m < 8; ++m) {
                acc[m][0] = MFMA(ah[m], b0h, acc[m][0]);
                acc[m][0] = MFMA(ah[m], b0l, acc[m][0]);
                acc[m][0] = MFMA(al[m], b0h, acc[m][0]);
            }
            if (ok1) {
                short8 b1h = ld8(bp1), b1l = ld8(bp1 + 512);
#pragma unroll
                for (int m = 0; m < 8; ++m) {
                    acc[m][1] = MFMA(ah[m], b1h, acc[m][1]);
                    acc[m][1] = MFMA(ah[m], b1l, acc[m][1]);
                    acc[m][1] = MFMA(al[m], b1h, acc[m][1]);
                }
            }
            ap += 8192; bp0 += 1024; bp1 += 1024;
        }
    }
    int rbase = (lane >> 4) << 2;
    int cof = lane & 15;
    float bw0 = ok0 ? bw[vtb * 16 + cof] : 0.f;
    float bw1 = ok1 ? bw[(vtb + 1) * 16 + cof] : 0.f;
#pragma unroll
    for (int m = 0; m < 8; ++m) {
#pragma unroll
        for (int r = 0; r < 4; ++r) {
            int row = m * 16 + rbase + r;
            u64 km = 0ull;
            if (ok0) {
                int v = vtb * 16 + cof;
                float x = acc[m][0][r] + bw0;
                out[((size_t)row * TMAX + t) * VOCAB + v] = x;
                km = ((u64)ford(x) << 32) | (u64)(0xFFFFFFFFu - (unsigned)v);
            }
            if (ok1) {
                int v = (vtb + 1) * 16 + cof;
                float x = acc[m][1][r] + bw1;
                out[((size_t)row * TMAX + t) * VOCAB + v] = x;
                u64 k2 = ((u64)ford(x) << 32) | (u64)(0xFFFFFFFFu - (unsigned)v);
                if (k2 > km) km = k2;
            }
#pragma unroll
            for (int s2 = 1; s2 <= 8; s2 <<= 1) {
                u64 o = __shfl_xor(km, s2, 64);
                if (o > km) km = o;
            }
            if ((lane & 15) == 0 && km) atomicMax(&keybuf[row], km);
        }
    }
    __syncthreads();
    if (tid < 128) atomicMax(&slots[(size_t)t * NSEQ + tid], keybuf[tid]);
}

__global__ void kact(const float* __restrict__ gates,
                     unsigned short* __restrict__ hfrag) {
    int n = blockIdx.x;
    int k = threadIdx.x;
    if (k >= WORD) return;
    const float* g = gates + (size_t)n * 1872;
    float gi = g[k], gg = g[620 + k], go = g[1240 + k];
    float si = 1.f / (1.f + expf(-gi));
    float so = 1.f / (1.f + expf(-go));
    float h = so * tanhf(si * tanhf(gg));
    int ks = k >> 5, mt = n >> 4;
    int lane = (n & 15) + (((k & 31) >> 3) << 4);
    int j = k & 7;
    size_t ob = (size_t)(ks * 8 + mt) * 1024 + lane * 8 + j;
    unsigned short hi = bf16rne(h);
    hfrag[ob] = hi;
    hfrag[ob + 512] = bf16rne(h - bf16tof(hi));
}

__global__ void kgather2(const float* __restrict__ embed,
                         const u64* __restrict__ slots,
                         unsigned short* __restrict__ lastfrag, int t) {
    int n = blockIdx.x;
    int k = threadIdx.x;
    if (k >= WORD) return;
    u64 s = slots[(size_t)t * NSEQ + n];
    unsigned idx = 0xFFFFFFFFu - (unsigned)(s & 0xFFFFFFFFull);
    float x = embed[(size_t)idx * WORD + k];
    int ks = k >> 5, mt = n >> 4;
    int lane = (n & 15) + (((k & 31) >> 3) << 4);
    int j = k & 7;
    size_t ob = (size_t)(ks * 8 + mt) * 1024 + lane * 8 + j;
    unsigned short hi = bf16rne(x);
    lastfrag[ob] = hi;
    lastfrag[ob + 512] = bf16rne(x - bf16tof(hi));
}

// =====================================================================
extern "C" void kernel_launch(void* const* d_in, const int* in_sizes, int n_in,
                              void* d_out, int out_size, void* d_ws, size_t ws_size,
                              hipStream_t stream) {
    const float* thoughts = (const float*)d_in[0];
    const float* embed    = (const float*)d_in[1];
    const float* W_ih     = (const float*)d_in[2];
    // d_in[3] = W_hh: dead (h0 == 0 always)
    const float* b_ih     = (const float*)d_in[4];
    const float* b_hh     = (const float*)d_in[5];
    const float* Ww       = (const float*)d_in[6];
    const float* bw       = (const float*)d_in[7];
    float* out = (float*)d_out;
    char* ws = (char*)d_ws;

    // mega layout
    const size_t OFF_WWF  = 0;              // 51,200,000
    const size_t OFF_WBF  = 51200000;       // 17,971,200
    const size_t OFF_WGF3 = 69171200;       //  4,792,320
    const size_t OFF_CTXF = 73963520;       //  1,228,800
    const size_t OFF_EHI  = 75192320;       // 25,600,000
    const size_t OFF_ELO  = 100792320;      // 25,600,000
    const size_t OFF_HF   = 126392320;      //    327,680
    const size_t OFF_BASE = 126720000;      //    958,464
    const size_t OFF_BSUM = 127678464;      //      7,488
    const size_t OFF_SLOT = 127685952;      //     30,720
    const size_t OFF_BAR  = 127716672;      //      2,048
    const size_t NEED_MEGA = 127718720;

    if (ws_size >= NEED_MEGA) {
        unsigned short* Wwf  = (unsigned short*)(ws + OFF_WWF);
        unsigned short* Wbf  = (unsigned short*)(ws + OFF_WBF);
        unsigned short* Wgf3 = (unsigned short*)(ws + OFF_WGF3);
        unsigned short* ctxf = (unsigned short*)(ws + OFF_CTXF);
        unsigned short* ehi  = (unsigned short*)(ws + OFF_EHI);
        unsigned short* elo  = (unsigned short*)(ws + OFF_ELO);
        unsigned short* hf   = (unsigned short*)(ws + OFF_HF);
        float* base = (float*)(ws + OFF_BASE);
        float* bsum = (float*)(ws + OFF_BSUM);
        u64*   slots = (u64*)(ws + OFF_SLOT);
        unsigned* bar = (unsigned*)(ws + OFF_BAR);

        kinit3<<<320, 256, 0, stream>>>((unsigned*)hf, (unsigned*)slots, bsum, bar, b_ih, b_hh);
        kpack_w<<<50000, 256, 0, stream>>>(Ww, Wwf, 1250, 20, 0, 620, WORD, VOCAB, 0);
        kpack_w<<<17550, 256, 0, stream>>>(W_ih, Wbf, 117, 75, 0, 2400, XK, 1860, 1);
        kpack_w<<<1560, 256, 0, stream>>>(W_ih + (size_t)0 * XK,    Wgf3 + 0 * 798720, 39, 20, 2400, 620, XK, 620, 0);
        kpack_w<<<1560, 256, 0, stream>>>(W_ih + (size_t)1240 * XK, Wgf3 + 1 * 798720, 39, 20, 2400, 620, XK, 620, 0);
        kpack_w<<<1560, 256, 0, stream>>>(W_ih + (size_t)1860 * XK, Wgf3 + 2 * 798720, 39, 20, 2400, 620, XK, 620, 0);
        kpack_ctx<<<1200, 256, 0, stream>>>(thoughts, ctxf);
        kpack_embed<<<50000, 256, 0, stream>>>(embed, ehi, elo);
        ggemm<<<15, 256, 0, stream>>>(ctxf, Wbf, bsum, nullptr, base, 75, 117, 1872);

        kmega<<<NBLK, 512, 0, stream>>>(ehi, elo, Wgf3, Wwf, base, bw, hf, slots, out, bar);
    } else {
        // round-2 fallback layout
        const size_t F_WWF  = 0;
        const size_t F_WBF  = 51200000;
        const size_t F_WGF  = 69171200;
        const size_t F_CTXF = 73963520;
        const size_t F_HF   = 75192320;
        const size_t F_LF   = 75520000;
        const size_t F_BASE = 75847680;
        const size_t F_GATE = 76806144;
        const size_t F_BSUM = 77764608;
        const size_t F_SLOT = 77772096;

        unsigned short* Wwf  = (unsigned short*)(ws + F_WWF);
        unsigned short* Wbf  = (unsigned short*)(ws + F_WBF);
        unsigned short* Wgf  = (unsigned short*)(ws + F_WGF);
        unsigned short* ctxf = (unsigned short*)(ws + F_CTXF);
        unsigned short* hf   = (unsigned short*)(ws + F_HF);
        unsigned short* lf   = (unsigned short*)(ws + F_LF);
        float* base = (float*)(ws + F_BASE);
        float* gate = (float*)(ws + F_GATE);
        float* bsum = (float*)(ws + F_BSUM);
        u64*   slots = (u64*)(ws + F_SLOT);

        kinit2<<<320, 256, 0, stream>>>((unsigned int*)lf, (unsigned int*)hf,
                                        (unsigned int*)slots, bsum, b_ih, b_hh);
        kpack_w<<<50000, 256, 0, stream>>>(Ww, Wwf, 1250, 20, 0, 620, WORD, VOCAB, 0);
        kpack_w<<<17550, 256, 0, stream>>>(W_ih, Wbf, 117, 75, 0, 2400, XK, 1860, 1);
        kpack_w<<<4680, 256, 0, stream>>>(W_ih, Wgf, 117, 20, 2400, 620, XK, 1860, 1);
        kpack_ctx<<<1200, 256, 0, stream>>>(thoughts, ctxf);
        ggemm<<<15, 256, 0, stream>>>(ctxf, Wbf, bsum, nullptr, base, 75, 117, 1872);
        for (int t = 0; t < TMAX; ++t) {
            ggemm<<<15, 256, 0, stream>>>(lf, Wgf, nullptr, base, gate, 20, 117, 1872);
            kact<<<NSEQ, 640, 0, stream>>>(gate, hf);
            klogits2<<<157, 256, 0, stream>>>(hf, Wwf, bw, out, slots, t);
            if (t + 1 < TMAX)
                kgather2<<<NSEQ, 640, 0, stream>>>(embed, slots, lf, t);
        }
    }
}